// Round 7
// baseline (456.471 us; speedup 1.0000x reference)
//
#include <hip/hip_runtime.h>

typedef __attribute__((ext_vector_type(8))) short bf16x8;
typedef __attribute__((ext_vector_type(4))) float f32x4;

// bf16 round-to-nearest-even
__device__ inline unsigned short bf16_rtn(float f) {
  unsigned u = __float_as_uint(f);
  unsigned r = u + 0x7fffu + ((u >> 16) & 1u);
  return (unsigned short)(r >> 16);
}

// split fp32 into hi/lo bf16 (for W only)
__device__ inline void split_bf16(float f, unsigned short& hi, unsigned short& lo) {
  hi = bf16_rtn(f);
  float fh = __uint_as_float((unsigned)hi << 16);
  lo = bf16_rtn(f - fh);
}

__device__ inline float bf16_to_f(unsigned short v) {
  return __uint_as_float((unsigned)v << 16);
}

// ---------------- CSR construction ----------------

__global__ void k_hist(const int* __restrict__ dst, int* __restrict__ deg, int E) {
  int e = blockIdx.x * 256 + threadIdx.x;
  if (e < E) atomicAdd(&deg[dst[e]], 1);
}

__global__ void k_scan1(const int* __restrict__ deg, int* __restrict__ rowptr,
                        int* __restrict__ bsum, float* __restrict__ dinv, int N) {
  __shared__ int s[256];
  int t = threadIdx.x;
  int i = blockIdx.x * 256 + t;
  int v = (i < N) ? deg[i] : 0;
  if (i < N) dinv[i] = rsqrtf((float)v + 1.0f);
  s[t] = v;
  __syncthreads();
  for (int off = 1; off < 256; off <<= 1) {
    int u = (t >= off) ? s[t - off] : 0;
    __syncthreads();
    s[t] += u;
    __syncthreads();
  }
  if (i < N) rowptr[i] = s[t] - v;
  if (t == 255) bsum[blockIdx.x] = s[255];
}

__global__ void k_scan2(const int* __restrict__ bsum, int* __restrict__ boff, int nb) {
  __shared__ int s[512];
  int t = threadIdx.x;
  int v = (t < nb) ? bsum[t] : 0;
  s[t] = v;
  __syncthreads();
  for (int off = 1; off < 512; off <<= 1) {
    int u = (t >= off) ? s[t - off] : 0;
    __syncthreads();
    s[t] += u;
    __syncthreads();
  }
  boff[t] = s[t] - v;
}

__global__ void k_scan3(int* __restrict__ rowptr, const int* __restrict__ boff,
                        int* __restrict__ cursor, int N, int E) {
  int i = blockIdx.x * 256 + threadIdx.x;
  if (i < N) {
    int r = rowptr[i] + boff[i >> 8];
    rowptr[i] = r;
    cursor[i] = r;
  }
  if (i == 0) rowptr[N] = E;
}

__global__ void k_scatter(const int* __restrict__ src, const int* __restrict__ dst,
                          const float* __restrict__ dinv, int* __restrict__ cursor,
                          int* __restrict__ esrc, float* __restrict__ ew, int E) {
  int e = blockIdx.x * 256 + threadIdx.x;
  if (e >= E) return;
  int s = src[e], d = dst[e];
  float w = dinv[s] * dinv[d];
  int pos = atomicAdd(&cursor[d], 1);
  esrc[pos] = s;
  ew[pos] = w;
}

// ---------------- tiny precomputes ----------------

// T[r][c] = embed[r] @ W0  (2 x 128)
__global__ void k_T(const float* __restrict__ embed, const float* __restrict__ W0,
                    float* __restrict__ T) {
  int t = threadIdx.x;
  int r = t >> 7, c = t & 127;
  float acc = 0.f;
  for (int k = 0; k < 128; ++k)
    acc += embed[r * 128 + k] * W0[k * 128 + c];
  T[r * 128 + c] = acc;
}

// Pre-swizzle W (layers 1..3) into MFMA B-fragment order, split hi/lo.
__global__ void k_prepW(const float* __restrict__ Ws,
                        unsigned short* __restrict__ wphi,
                        unsigned short* __restrict__ wplo) {
  int l = blockIdx.x;              // 0..2 -> layers 1..3
  const float* W = Ws + (size_t)(l + 1) * 128 * 128;
  unsigned short* dh = wphi + (size_t)l * 16384;
  unsigned short* dl = wplo + (size_t)l * 16384;
  for (int idx = threadIdx.x; idx < 16384; idx += 256) {
    int j = idx & 7;
    int lane = (idx >> 3) & 63;
    int c = (idx >> 9) & 3;
    int ct = idx >> 11;
    int k = c * 32 + ((lane >> 4) * 8) + j;
    int n = ct * 16 + (lane & 15);
    unsigned short hi, lo;
    split_bf16(W[k * 128 + n], hi, lo);
    dh[idx] = hi;
    dl[idx] = lo;
  }
}

__global__ void k_bounds(const int* __restrict__ batch, int* __restrict__ gstart,
                         int* __restrict__ gend, int N) {
  int i = blockIdx.x * 256 + threadIdx.x;
  if (i >= N) return;
  int g = batch[i];
  if (i == 0 || batch[i - 1] != g) gstart[g] = i;
  if (i == N - 1 || batch[i + 1] != g) gend[g] = i + 1;
}

// ---------------- shared MFMA phase: t_out tile = hT(LDS) @ W' ----------------
__device__ inline void gemm_tile(const unsigned short* hT,
                                 const unsigned short* __restrict__ wphi,
                                 const unsigned short* __restrict__ wplo,
                                 unsigned short* __restrict__ tout, int i0, int N) {
  int wave = threadIdx.x >> 6;
  int lane = threadIdx.x & 63;
  int q = lane >> 4;
  int m = lane & 15;
  const bf16x8* bh_base = (const bf16x8*)wphi;
  const bf16x8* bl_base = (const bf16x8*)wplo;

  f32x4 acc[2][2];
  #pragma unroll
  for (int tt = 0; tt < 2; ++tt)
    #pragma unroll
    for (int cc = 0; cc < 2; ++cc)
      acc[tt][cc] = (f32x4){0.f, 0.f, 0.f, 0.f};

  #pragma unroll
  for (int c = 0; c < 4; ++c) {
    bf16x8 a0 = *(const bf16x8*)(hT + (m) * 136 + c * 32 + q * 8);
    bf16x8 a1 = *(const bf16x8*)(hT + (16 + m) * 136 + c * 32 + q * 8);
    #pragma unroll
    for (int cc = 0; cc < 2; ++cc) {
      int ct = wave * 2 + cc;
      bf16x8 bh = bh_base[(ct * 4 + c) * 64 + lane];
      bf16x8 bl = bl_base[(ct * 4 + c) * 64 + lane];
      acc[0][cc] = __builtin_amdgcn_mfma_f32_16x16x32_bf16(a0, bh, acc[0][cc], 0, 0, 0);
      acc[0][cc] = __builtin_amdgcn_mfma_f32_16x16x32_bf16(a0, bl, acc[0][cc], 0, 0, 0);
      acc[1][cc] = __builtin_amdgcn_mfma_f32_16x16x32_bf16(a1, bh, acc[1][cc], 0, 0, 0);
      acc[1][cc] = __builtin_amdgcn_mfma_f32_16x16x32_bf16(a1, bl, acc[1][cc], 0, 0, 0);
    }
  }

  #pragma unroll
  for (int tt = 0; tt < 2; ++tt)
    #pragma unroll
    for (int cc = 0; cc < 2; ++cc)
      #pragma unroll
      for (int r = 0; r < 4; ++r) {
        int row = i0 + tt * 16 + q * 4 + r;
        if (row < N)
          tout[(size_t)row * 128 + (wave * 2 + cc) * 16 + m] = bf16_rtn(acc[tt][cc][r]);
      }
}

// ---------------- fused layer0 (rank-2) + gemm1: t1 = h1 @ W1 ----------------
__global__ void k_l1_gemm(const int* __restrict__ x, const int* __restrict__ rowptr,
                          const int* __restrict__ esrc, const float* __restrict__ ew,
                          const float* __restrict__ dinv, const float* __restrict__ T,
                          const float* __restrict__ b0,
                          const unsigned short* __restrict__ wphi,
                          const unsigned short* __restrict__ wplo,
                          unsigned short* __restrict__ tout, int N) {
  __shared__ unsigned short hT[32 * 136];
  int wave = threadIdx.x >> 6;
  int lane = threadIdx.x & 63;
  int i0 = blockIdx.x * 32;

  for (int j = wave * 8; j < wave * 8 + 8; ++j) {
    int i = i0 + j;
    if (i >= N) break;
    int r0 = rowptr[i], r1 = rowptr[i + 1];
    float c0 = 0.f, c1 = 0.f;
    for (int e = r0 + lane; e < r1; e += 64) {
      float w = ew[e];
      int s = esrc[e];
      if (x[s]) c1 += w; else c0 += w;
    }
    for (int mm = 32; mm >= 1; mm >>= 1) {
      c0 += __shfl_xor(c0, mm, 64);
      c1 += __shfl_xor(c1, mm, 64);
    }
    float di = dinv[i];
    float sn = di * di;
    if (x[i]) c1 += sn; else c0 += sn;
    float v0 = fmaxf(c0 * T[2 * lane]     + c1 * T[128 + 2 * lane]     + b0[2 * lane],     0.f);
    float v1 = fmaxf(c0 * T[2 * lane + 1] + c1 * T[128 + 2 * lane + 1] + b0[2 * lane + 1], 0.f);
    *(unsigned*)&hT[j * 136 + 2 * lane] = (unsigned)bf16_rtn(v0) | ((unsigned)bf16_rtn(v1) << 16);
  }
  __syncthreads();
  gemm_tile(hT, wphi, wplo, tout, i0, N);
}

// ---------------- interleaved 8-node gather (wave-cooperative, high MLP) ----------------
// Computes a0[n], a1[n] = aggregated columns (2*lane, 2*lane+1) for nodes i0w+n.
// All per-n loop guards are wave-uniform. Loads across n are independent.
__device__ inline void gather8(const unsigned short* __restrict__ tin,
                               const int* __restrict__ rowptr,
                               const int* __restrict__ esrc, const float* __restrict__ ew,
                               const float* __restrict__ dinv,
                               int i0w, int lane, int N,
                               float (&a0)[8], float (&a1)[8]) {
  int r0[8], dcap[8], dext[8];
  int sl[8]; float wl[8];
  unsigned ps[8]; float di[8];
  #pragma unroll
  for (int n = 0; n < 8; ++n) {
    int i = i0w + n;
    bool val = i < N;
    int rr0 = val ? rowptr[i] : 0;
    int rr1 = val ? rowptr[i + 1] : 0;
    r0[n] = rr0;
    int dg = rr1 - rr0;
    dcap[n] = dg < 64 ? dg : 64;
    dext[n] = dg - dcap[n];
    a0[n] = 0.f; a1[n] = 0.f;
    sl[n] = 0; wl[n] = 0.f;
    if (lane < dcap[n]) { sl[n] = esrc[rr0 + lane]; wl[n] = ew[rr0 + lane]; }
    di[n] = val ? dinv[i] : 0.f;
    ps[n] = val ? *(const unsigned*)(tin + (size_t)i * 128 + 2 * lane) : 0u;
  }
  int maxd = 0;
  #pragma unroll
  for (int n = 0; n < 8; ++n) maxd = dcap[n] > maxd ? dcap[n] : maxd;

  for (int e = 0; e < maxd; ++e) {
    #pragma unroll
    for (int n = 0; n < 8; ++n) {
      if (e < dcap[n]) {                       // wave-uniform guard
        int s = __shfl(sl[n], e, 64);
        float w = __shfl(wl[n], e, 64);
        unsigned p = *(const unsigned*)(tin + (size_t)s * 128 + 2 * lane);
        a0[n] += w * bf16_to_f((unsigned short)(p & 0xffffu));
        a1[n] += w * bf16_to_f((unsigned short)(p >> 16));
      }
    }
  }
  #pragma unroll
  for (int n = 0; n < 8; ++n) {
    if (dext[n] > 0) {                         // rare: deg > 64
      for (int e = r0[n] + 64; e < r0[n] + 64 + dext[n]; ++e) {
        int s = esrc[e];
        float w = ew[e];
        unsigned p = *(const unsigned*)(tin + (size_t)s * 128 + 2 * lane);
        a0[n] += w * bf16_to_f((unsigned short)(p & 0xffffu));
        a1[n] += w * bf16_to_f((unsigned short)(p >> 16));
      }
    }
  }
  #pragma unroll
  for (int n = 0; n < 8; ++n) {
    float sn = di[n] * di[n];
    a0[n] += sn * bf16_to_f((unsigned short)(ps[n] & 0xffffu));
    a1[n] += sn * bf16_to_f((unsigned short)(ps[n] >> 16));
  }
}

// ---------------- fused aggregate + gemm: t_next = relu(A t_in + b) @ W' ----------------
__global__ void k_agg_gemm(const unsigned short* __restrict__ tin,
                           const int* __restrict__ rowptr,
                           const int* __restrict__ esrc, const float* __restrict__ ew,
                           const float* __restrict__ dinv, const float* __restrict__ bvec,
                           const unsigned short* __restrict__ wphi,
                           const unsigned short* __restrict__ wplo,
                           unsigned short* __restrict__ tout, int N) {
  __shared__ unsigned short hT[32 * 136];
  int wave = threadIdx.x >> 6;
  int lane = threadIdx.x & 63;
  int i0 = blockIdx.x * 32;
  int i0w = i0 + wave * 8;
  float2 bv = *(const float2*)(bvec + 2 * lane);

  float a0[8], a1[8];
  gather8(tin, rowptr, esrc, ew, dinv, i0w, lane, N, a0, a1);

  #pragma unroll
  for (int n = 0; n < 8; ++n) {
    if (i0w + n < N) {
      float v0 = fmaxf(a0[n] + bv.x, 0.f);
      float v1 = fmaxf(a1[n] + bv.y, 0.f);
      *(unsigned*)&hT[(wave * 8 + n) * 136 + 2 * lane] =
          (unsigned)bf16_rtn(v0) | ((unsigned)bf16_rtn(v1) << 16);
    }
  }
  __syncthreads();
  gemm_tile(hT, wphi, wplo, tout, i0, N);
}

// ---------------- fused final aggregate + segment mean-pool ----------------
__global__ void k_agg_pool(const unsigned short* __restrict__ tin,
                           const int* __restrict__ rowptr,
                           const int* __restrict__ esrc, const float* __restrict__ ew,
                           const float* __restrict__ dinv, const float* __restrict__ bvec,
                           const int* __restrict__ batch,
                           float* __restrict__ pooled, int N) {
  int wave = threadIdx.x >> 6;
  int lane = threadIdx.x & 63;
  int i0w = blockIdx.x * 32 + wave * 8;
  if (i0w >= N) return;
  float2 bv = *(const float2*)(bvec + 2 * lane);

  float a0[8], a1[8];
  gather8(tin, rowptr, esrc, ew, dinv, i0w, lane, N, a0, a1);

  float acc0 = 0.f, acc1 = 0.f;
  int curg = batch[i0w];
  #pragma unroll
  for (int n = 0; n < 8; ++n) {
    int i = i0w + n;
    if (i < N) {
      int g = batch[i];
      if (g != curg) {
        atomicAdd(&pooled[curg * 128 + 2 * lane], acc0);
        atomicAdd(&pooled[curg * 128 + 2 * lane + 1], acc1);
        acc0 = 0.f; acc1 = 0.f;
        curg = g;
      }
      acc0 += a0[n] + bv.x;
      acc1 += a1[n] + bv.y;
    }
  }
  atomicAdd(&pooled[curg * 128 + 2 * lane], acc0);
  atomicAdd(&pooled[curg * 128 + 2 * lane + 1], acc1);
}

// ---------------- output head ----------------
__global__ void k_out(const float* __restrict__ pooled, const int* __restrict__ gstart,
                      const int* __restrict__ gend, const float* __restrict__ W_out,
                      const float* __restrict__ b_out, float* __restrict__ out, int G) {
  __shared__ float sp[128];
  int g = blockIdx.x;
  int j = threadIdx.x;
  float cnt = (float)(gend[g] - gstart[g]);
  sp[j] = pooled[g * 128 + j] / fmaxf(cnt, 1.f);
  __syncthreads();
  if (j < 2) {
    float o = b_out[j];
    for (int k = 0; k < 128; ++k)
      o += sp[k] * W_out[k * 2 + j];
    out[g * 2 + j] = o;
  }
}

extern "C" void kernel_launch(void* const* d_in, const int* in_sizes, int n_in,
                              void* d_out, int out_size, void* d_ws, size_t ws_size,
                              hipStream_t stream) {
  const int*   x     = (const int*)d_in[0];
  const int*   ei    = (const int*)d_in[1];
  const int*   batch = (const int*)d_in[2];
  const float* embed = (const float*)d_in[3];
  const float* Ws    = (const float*)d_in[4];
  const float* bs    = (const float*)d_in[5];
  const float* W_out = (const float*)d_in[6];
  const float* b_out = (const float*)d_in[7];
  float* out = (float*)d_out;

  int N = in_sizes[2];
  int E = in_sizes[1] / 2;
  int G = out_size / 2;

  const int* src = ei;
  const int* dst = ei + E;

  char* w = (char*)d_ws;
  auto alloc = [&](size_t bytes) {
    char* p = w;
    w += (bytes + 255) & ~(size_t)255;
    return p;
  };
  int*   deg    = (int*)  alloc((size_t)N * 4);
  float* dinv   = (float*)alloc((size_t)N * 4);
  int*   rowptr = (int*)  alloc((size_t)(N + 1) * 4);
  int*   cursor = (int*)  alloc((size_t)N * 4);
  int*   bsum   = (int*)  alloc(512 * 4);
  int*   boff   = (int*)  alloc(512 * 4);
  // gstart/gend/pooled contiguous -> single memset
  int*   gstart = (int*)  alloc((size_t)G * 4);
  int*   gend   = (int*)  alloc((size_t)G * 4);
  float* pooled = (float*)alloc((size_t)G * 128 * 4);
  float* T      = (float*)alloc(256 * 4);
  unsigned short* wphi = (unsigned short*)alloc((size_t)3 * 16384 * 2);
  unsigned short* wplo = (unsigned short*)alloc((size_t)3 * 16384 * 2);
  int*   esrc   = (int*)  alloc((size_t)E * 4);
  float* eww    = (float*)alloc((size_t)E * 4);
  unsigned short* t_a = (unsigned short*)alloc((size_t)N * 128 * 2);
  unsigned short* t_b = (unsigned short*)alloc((size_t)N * 128 * 2);

  int nbN = (N + 255) / 256;
  int nbE = (E + 255) / 256;
  int ntile = (N + 31) / 32;

  size_t gzero = (size_t)((char*)pooled - (char*)gstart) + (size_t)G * 128 * 4;
  hipMemsetAsync(deg, 0, (size_t)N * 4, stream);
  hipMemsetAsync(gstart, 0, gzero, stream);

  k_hist<<<nbE, 256, 0, stream>>>(dst, deg, E);
  k_scan1<<<nbN, 256, 0, stream>>>(deg, rowptr, bsum, dinv, N);
  k_scan2<<<1, 512, 0, stream>>>(bsum, boff, nbN);
  k_scan3<<<nbN, 256, 0, stream>>>(rowptr, boff, cursor, N, E);
  k_scatter<<<nbE, 256, 0, stream>>>(src, dst, dinv, cursor, esrc, eww, E);
  k_T<<<1, 256, 0, stream>>>(embed, Ws, T);
  k_prepW<<<3, 256, 0, stream>>>(Ws, wphi, wplo);
  k_bounds<<<nbN, 256, 0, stream>>>(batch, gstart, gend, N);

  // layer0 (rank-2) + gemm1 -> t_a
  k_l1_gemm<<<ntile, 256, 0, stream>>>(x, rowptr, esrc, eww, dinv, T, bs,
                                       wphi, wplo, t_a, N);
  // agg(b1)+gemm(W2) -> t_b ; agg(b2)+gemm(W3) -> t_a
  k_agg_gemm<<<ntile, 256, 0, stream>>>(t_a, rowptr, esrc, eww, dinv, bs + 128,
                                        wphi + 16384, wplo + 16384, t_b, N);
  k_agg_gemm<<<ntile, 256, 0, stream>>>(t_b, rowptr, esrc, eww, dinv, bs + 256,
                                        wphi + 32768, wplo + 32768, t_a, N);
  // final agg(b3) + mean-pool
  k_agg_pool<<<ntile, 256, 0, stream>>>(t_a, rowptr, esrc, eww, dinv, bs + 384,
                                        batch, pooled, N);
  k_out<<<G, 128, 0, stream>>>(pooled, gstart, gend, W_out, b_out, out, G);
}

// Round 8
// 370.493 us; speedup vs baseline: 1.2321x; 1.2321x over previous
//
#include <hip/hip_runtime.h>

typedef __attribute__((ext_vector_type(8))) short bf16x8;
typedef __attribute__((ext_vector_type(4))) float f32x4;

// bf16 round-to-nearest-even
__device__ inline unsigned short bf16_rtn(float f) {
  unsigned u = __float_as_uint(f);
  unsigned r = u + 0x7fffu + ((u >> 16) & 1u);
  return (unsigned short)(r >> 16);
}

// split fp32 into hi/lo bf16 (for W only)
__device__ inline void split_bf16(float f, unsigned short& hi, unsigned short& lo) {
  hi = bf16_rtn(f);
  float fh = __uint_as_float((unsigned)hi << 16);
  lo = bf16_rtn(f - fh);
}

__device__ inline float bf16_to_f(unsigned short v) {
  return __uint_as_float((unsigned)v << 16);
}

// ---------------- CSR construction ----------------

__global__ void k_hist(const int* __restrict__ dst, int* __restrict__ deg, int E) {
  int e = blockIdx.x * 256 + threadIdx.x;
  if (e < E) atomicAdd(&deg[dst[e]], 1);
}

__global__ void k_scan1(const int* __restrict__ deg, int* __restrict__ rowptr,
                        int* __restrict__ bsum, float* __restrict__ dinv, int N) {
  __shared__ int s[256];
  int t = threadIdx.x;
  int i = blockIdx.x * 256 + t;
  int v = (i < N) ? deg[i] : 0;
  if (i < N) dinv[i] = rsqrtf((float)v + 1.0f);
  s[t] = v;
  __syncthreads();
  for (int off = 1; off < 256; off <<= 1) {
    int u = (t >= off) ? s[t - off] : 0;
    __syncthreads();
    s[t] += u;
    __syncthreads();
  }
  if (i < N) rowptr[i] = s[t] - v;
  if (t == 255) bsum[blockIdx.x] = s[255];
}

__global__ void k_scan2(const int* __restrict__ bsum, int* __restrict__ boff, int nb) {
  __shared__ int s[512];
  int t = threadIdx.x;
  int v = (t < nb) ? bsum[t] : 0;
  s[t] = v;
  __syncthreads();
  for (int off = 1; off < 512; off <<= 1) {
    int u = (t >= off) ? s[t - off] : 0;
    __syncthreads();
    s[t] += u;
    __syncthreads();
  }
  boff[t] = s[t] - v;
}

__global__ void k_scan3(int* __restrict__ rowptr, const int* __restrict__ boff,
                        int* __restrict__ cursor, int N, int E) {
  int i = blockIdx.x * 256 + threadIdx.x;
  if (i < N) {
    int r = rowptr[i] + boff[i >> 8];
    rowptr[i] = r;
    cursor[i] = r;
  }
  if (i == 0) rowptr[N] = E;
}

__global__ void k_scatter(const int* __restrict__ src, const int* __restrict__ dst,
                          const float* __restrict__ dinv, int* __restrict__ cursor,
                          int* __restrict__ esrc, float* __restrict__ ew, int E) {
  int e = blockIdx.x * 256 + threadIdx.x;
  if (e >= E) return;
  int s = src[e], d = dst[e];
  float w = dinv[s] * dinv[d];
  int pos = atomicAdd(&cursor[d], 1);
  esrc[pos] = s;
  ew[pos] = w;
}

// ---------------- tiny precomputes ----------------

// T[r][c] = embed[r] @ W0  (2 x 128)
__global__ void k_T(const float* __restrict__ embed, const float* __restrict__ W0,
                    float* __restrict__ T) {
  int t = threadIdx.x;
  int r = t >> 7, c = t & 127;
  float acc = 0.f;
  for (int k = 0; k < 128; ++k)
    acc += embed[r * 128 + k] * W0[k * 128 + c];
  T[r * 128 + c] = acc;
}

// Pre-swizzle W (layers 1..3) into MFMA B-fragment order, split hi/lo.
__global__ void k_prepW(const float* __restrict__ Ws,
                        unsigned short* __restrict__ wphi,
                        unsigned short* __restrict__ wplo) {
  int l = blockIdx.x;              // 0..2 -> layers 1..3
  const float* W = Ws + (size_t)(l + 1) * 128 * 128;
  unsigned short* dh = wphi + (size_t)l * 16384;
  unsigned short* dl = wplo + (size_t)l * 16384;
  for (int idx = threadIdx.x; idx < 16384; idx += 256) {
    int j = idx & 7;
    int lane = (idx >> 3) & 63;
    int c = (idx >> 9) & 3;
    int ct = idx >> 11;
    int k = c * 32 + ((lane >> 4) * 8) + j;
    int n = ct * 16 + (lane & 15);
    unsigned short hi, lo;
    split_bf16(W[k * 128 + n], hi, lo);
    dh[idx] = hi;
    dl[idx] = lo;
  }
}

__global__ void k_bounds(const int* __restrict__ batch, int* __restrict__ gstart,
                         int* __restrict__ gend, int N) {
  int i = blockIdx.x * 256 + threadIdx.x;
  if (i >= N) return;
  int g = batch[i];
  if (i == 0 || batch[i - 1] != g) gstart[g] = i;
  if (i == N - 1 || batch[i + 1] != g) gend[g] = i + 1;
}

// ---------------- per-node gather, unroll-4 batched loads ----------------
__device__ inline void gather_node(const unsigned short* __restrict__ tin,
                                   const int* __restrict__ esrc,
                                   const float* __restrict__ ew,
                                   int r0, int deg, int lane,
                                   float& a0, float& a1) {
  int dcap = deg < 64 ? deg : 64;
  int sl = 0; float wl = 0.f;
  if (lane < dcap) { sl = esrc[r0 + lane]; wl = ew[r0 + lane]; }
  a0 = 0.f; a1 = 0.f;
  int e = 0;
  for (; e + 4 <= dcap; e += 4) {
    int s0 = __shfl(sl, e, 64),     s1 = __shfl(sl, e + 1, 64);
    int s2 = __shfl(sl, e + 2, 64), s3 = __shfl(sl, e + 3, 64);
    float w0 = __shfl(wl, e, 64),     w1 = __shfl(wl, e + 1, 64);
    float w2 = __shfl(wl, e + 2, 64), w3 = __shfl(wl, e + 3, 64);
    unsigned p0 = *(const unsigned*)(tin + (size_t)s0 * 128 + 2 * lane);
    unsigned p1 = *(const unsigned*)(tin + (size_t)s1 * 128 + 2 * lane);
    unsigned p2 = *(const unsigned*)(tin + (size_t)s2 * 128 + 2 * lane);
    unsigned p3 = *(const unsigned*)(tin + (size_t)s3 * 128 + 2 * lane);
    a0 += w0 * bf16_to_f((unsigned short)(p0 & 0xffffu))
        + w1 * bf16_to_f((unsigned short)(p1 & 0xffffu))
        + w2 * bf16_to_f((unsigned short)(p2 & 0xffffu))
        + w3 * bf16_to_f((unsigned short)(p3 & 0xffffu));
    a1 += w0 * bf16_to_f((unsigned short)(p0 >> 16))
        + w1 * bf16_to_f((unsigned short)(p1 >> 16))
        + w2 * bf16_to_f((unsigned short)(p2 >> 16))
        + w3 * bf16_to_f((unsigned short)(p3 >> 16));
  }
  for (; e < dcap; ++e) {
    int s = __shfl(sl, e, 64);
    float w = __shfl(wl, e, 64);
    unsigned p = *(const unsigned*)(tin + (size_t)s * 128 + 2 * lane);
    a0 += w * bf16_to_f((unsigned short)(p & 0xffffu));
    a1 += w * bf16_to_f((unsigned short)(p >> 16));
  }
  for (int ee = r0 + 64; ee < r0 + deg; ++ee) {   // rare: deg > 64
    int s = esrc[ee];
    float w = ew[ee];
    unsigned p = *(const unsigned*)(tin + (size_t)s * 128 + 2 * lane);
    a0 += w * bf16_to_f((unsigned short)(p & 0xffffu));
    a1 += w * bf16_to_f((unsigned short)(p >> 16));
  }
}

// ---------------- shared MFMA phase (8 waves, ct = wave): tile = hT @ W' ----------------
__device__ inline void gemm_tile8(const unsigned short* hT,
                                  const unsigned short* __restrict__ wphi,
                                  const unsigned short* __restrict__ wplo,
                                  unsigned short* __restrict__ tout, int i0, int N) {
  int ct = threadIdx.x >> 6;     // wave 0..7 -> 16-col stripe
  int lane = threadIdx.x & 63;
  int q = lane >> 4;
  int m = lane & 15;
  const bf16x8* bh_base = (const bf16x8*)wphi;
  const bf16x8* bl_base = (const bf16x8*)wplo;

  f32x4 acc0 = (f32x4){0.f, 0.f, 0.f, 0.f};
  f32x4 acc1 = (f32x4){0.f, 0.f, 0.f, 0.f};

  #pragma unroll
  for (int c = 0; c < 4; ++c) {
    bf16x8 a0 = *(const bf16x8*)(hT + (m) * 136 + c * 32 + q * 8);
    bf16x8 a1 = *(const bf16x8*)(hT + (16 + m) * 136 + c * 32 + q * 8);
    bf16x8 bh = bh_base[(ct * 4 + c) * 64 + lane];
    bf16x8 bl = bl_base[(ct * 4 + c) * 64 + lane];
    acc0 = __builtin_amdgcn_mfma_f32_16x16x32_bf16(a0, bh, acc0, 0, 0, 0);
    acc0 = __builtin_amdgcn_mfma_f32_16x16x32_bf16(a0, bl, acc0, 0, 0, 0);
    acc1 = __builtin_amdgcn_mfma_f32_16x16x32_bf16(a1, bh, acc1, 0, 0, 0);
    acc1 = __builtin_amdgcn_mfma_f32_16x16x32_bf16(a1, bl, acc1, 0, 0, 0);
  }

  #pragma unroll
  for (int r = 0; r < 4; ++r) {
    int row0 = i0 + q * 4 + r;
    int row1 = row0 + 16;
    if (row0 < N) tout[(size_t)row0 * 128 + ct * 16 + m] = bf16_rtn(acc0[r]);
    if (row1 < N) tout[(size_t)row1 * 128 + ct * 16 + m] = bf16_rtn(acc1[r]);
  }
}

// ---------------- fused layer0 (rank-2) + gemm1: t1 = h1 @ W1 ----------------
__global__ __launch_bounds__(512)
void k_l1_gemm(const int* __restrict__ x, const int* __restrict__ rowptr,
               const int* __restrict__ esrc, const float* __restrict__ ew,
               const float* __restrict__ dinv, const float* __restrict__ T,
               const float* __restrict__ b0,
               const unsigned short* __restrict__ wphi,
               const unsigned short* __restrict__ wplo,
               unsigned short* __restrict__ tout, int N) {
  __shared__ unsigned short hT[32 * 136];
  int wave = threadIdx.x >> 6;
  int lane = threadIdx.x & 63;
  int i0 = blockIdx.x * 32;

  for (int j = wave * 4; j < wave * 4 + 4; ++j) {
    int i = i0 + j;
    if (i >= N) break;
    int r0 = rowptr[i], r1 = rowptr[i + 1];
    float c0 = 0.f, c1 = 0.f;
    for (int e = r0 + lane; e < r1; e += 64) {
      float w = ew[e];
      int s = esrc[e];
      if (x[s]) c1 += w; else c0 += w;
    }
    for (int mm = 32; mm >= 1; mm >>= 1) {
      c0 += __shfl_xor(c0, mm, 64);
      c1 += __shfl_xor(c1, mm, 64);
    }
    float di = dinv[i];
    float sn = di * di;
    if (x[i]) c1 += sn; else c0 += sn;
    float v0 = fmaxf(c0 * T[2 * lane]     + c1 * T[128 + 2 * lane]     + b0[2 * lane],     0.f);
    float v1 = fmaxf(c0 * T[2 * lane + 1] + c1 * T[128 + 2 * lane + 1] + b0[2 * lane + 1], 0.f);
    *(unsigned*)&hT[j * 136 + 2 * lane] = (unsigned)bf16_rtn(v0) | ((unsigned)bf16_rtn(v1) << 16);
  }
  __syncthreads();
  gemm_tile8(hT, wphi, wplo, tout, i0, N);
}

// ---------------- fused aggregate + gemm: t_next = relu(A t_in + b) @ W' ----------------
__global__ __launch_bounds__(512)
void k_agg_gemm(const unsigned short* __restrict__ tin,
                const int* __restrict__ rowptr,
                const int* __restrict__ esrc, const float* __restrict__ ew,
                const float* __restrict__ dinv, const float* __restrict__ bvec,
                const unsigned short* __restrict__ wphi,
                const unsigned short* __restrict__ wplo,
                unsigned short* __restrict__ tout, int N) {
  __shared__ unsigned short hT[32 * 136];
  int wave = threadIdx.x >> 6;
  int lane = threadIdx.x & 63;
  int i0 = blockIdx.x * 32;
  float2 bv = *(const float2*)(bvec + 2 * lane);

  for (int j = wave * 4; j < wave * 4 + 4; ++j) {
    int i = i0 + j;
    if (i >= N) break;
    int r0 = rowptr[i], r1 = rowptr[i + 1];
    float a0, a1;
    gather_node(tin, esrc, ew, r0, r1 - r0, lane, a0, a1);
    float di = dinv[i];
    float sn = di * di;
    unsigned ps = *(const unsigned*)(tin + (size_t)i * 128 + 2 * lane);
    a0 += sn * bf16_to_f((unsigned short)(ps & 0xffffu));
    a1 += sn * bf16_to_f((unsigned short)(ps >> 16));
    float v0 = fmaxf(a0 + bv.x, 0.f);
    float v1 = fmaxf(a1 + bv.y, 0.f);
    *(unsigned*)&hT[j * 136 + 2 * lane] = (unsigned)bf16_rtn(v0) | ((unsigned)bf16_rtn(v1) << 16);
  }
  __syncthreads();
  gemm_tile8(hT, wphi, wplo, tout, i0, N);
}

// ---------------- fused final aggregate + segment mean-pool ----------------
__global__ __launch_bounds__(512)
void k_agg_pool(const unsigned short* __restrict__ tin,
                const int* __restrict__ rowptr,
                const int* __restrict__ esrc, const float* __restrict__ ew,
                const float* __restrict__ dinv, const float* __restrict__ bvec,
                const int* __restrict__ batch,
                float* __restrict__ pooled, int N) {
  int wave = threadIdx.x >> 6;
  int lane = threadIdx.x & 63;
  int i0w = blockIdx.x * 32 + wave * 4;
  if (i0w >= N) return;
  float2 bv = *(const float2*)(bvec + 2 * lane);

  float acc0 = 0.f, acc1 = 0.f;
  int curg = batch[i0w];
  for (int n = 0; n < 4; ++n) {
    int i = i0w + n;
    if (i >= N) break;
    int r0 = rowptr[i], r1 = rowptr[i + 1];
    float a0, a1;
    gather_node(tin, esrc, ew, r0, r1 - r0, lane, a0, a1);
    float di = dinv[i];
    float sn = di * di;
    unsigned ps = *(const unsigned*)(tin + (size_t)i * 128 + 2 * lane);
    a0 += sn * bf16_to_f((unsigned short)(ps & 0xffffu)) + bv.x;
    a1 += sn * bf16_to_f((unsigned short)(ps >> 16)) + bv.y;
    int g = batch[i];
    if (g != curg) {
      atomicAdd(&pooled[curg * 128 + 2 * lane], acc0);
      atomicAdd(&pooled[curg * 128 + 2 * lane + 1], acc1);
      acc0 = 0.f; acc1 = 0.f;
      curg = g;
    }
    acc0 += a0;
    acc1 += a1;
  }
  atomicAdd(&pooled[curg * 128 + 2 * lane], acc0);
  atomicAdd(&pooled[curg * 128 + 2 * lane + 1], acc1);
}

// ---------------- output head ----------------
__global__ void k_out(const float* __restrict__ pooled, const int* __restrict__ gstart,
                      const int* __restrict__ gend, const float* __restrict__ W_out,
                      const float* __restrict__ b_out, float* __restrict__ out, int G) {
  __shared__ float sp[128];
  int g = blockIdx.x;
  int j = threadIdx.x;
  float cnt = (float)(gend[g] - gstart[g]);
  sp[j] = pooled[g * 128 + j] / fmaxf(cnt, 1.f);
  __syncthreads();
  if (j < 2) {
    float o = b_out[j];
    for (int k = 0; k < 128; ++k)
      o += sp[k] * W_out[k * 2 + j];
    out[g * 2 + j] = o;
  }
}

extern "C" void kernel_launch(void* const* d_in, const int* in_sizes, int n_in,
                              void* d_out, int out_size, void* d_ws, size_t ws_size,
                              hipStream_t stream) {
  const int*   x     = (const int*)d_in[0];
  const int*   ei    = (const int*)d_in[1];
  const int*   batch = (const int*)d_in[2];
  const float* embed = (const float*)d_in[3];
  const float* Ws    = (const float*)d_in[4];
  const float* bs    = (const float*)d_in[5];
  const float* W_out = (const float*)d_in[6];
  const float* b_out = (const float*)d_in[7];
  float* out = (float*)d_out;

  int N = in_sizes[2];
  int E = in_sizes[1] / 2;
  int G = out_size / 2;

  const int* src = ei;
  const int* dst = ei + E;

  char* w = (char*)d_ws;
  auto alloc = [&](size_t bytes) {
    char* p = w;
    w += (bytes + 255) & ~(size_t)255;
    return p;
  };
  int*   deg    = (int*)  alloc((size_t)N * 4);
  float* dinv   = (float*)alloc((size_t)N * 4);
  int*   rowptr = (int*)  alloc((size_t)(N + 1) * 4);
  int*   cursor = (int*)  alloc((size_t)N * 4);
  int*   bsum   = (int*)  alloc(512 * 4);
  int*   boff   = (int*)  alloc(512 * 4);
  // gstart/gend/pooled contiguous -> single memset
  int*   gstart = (int*)  alloc((size_t)G * 4);
  int*   gend   = (int*)  alloc((size_t)G * 4);
  float* pooled = (float*)alloc((size_t)G * 128 * 4);
  float* T      = (float*)alloc(256 * 4);
  unsigned short* wphi = (unsigned short*)alloc((size_t)3 * 16384 * 2);
  unsigned short* wplo = (unsigned short*)alloc((size_t)3 * 16384 * 2);
  int*   esrc   = (int*)  alloc((size_t)E * 4);
  float* eww    = (float*)alloc((size_t)E * 4);
  unsigned short* t_a = (unsigned short*)alloc((size_t)N * 128 * 2);
  unsigned short* t_b = (unsigned short*)alloc((size_t)N * 128 * 2);

  int nbN = (N + 255) / 256;
  int nbE = (E + 255) / 256;
  int ntile = (N + 31) / 32;

  size_t gzero = (size_t)((char*)pooled - (char*)gstart) + (size_t)G * 128 * 4;
  hipMemsetAsync(deg, 0, (size_t)N * 4, stream);
  hipMemsetAsync(gstart, 0, gzero, stream);

  k_hist<<<nbE, 256, 0, stream>>>(dst, deg, E);
  k_scan1<<<nbN, 256, 0, stream>>>(deg, rowptr, bsum, dinv, N);
  k_scan2<<<1, 512, 0, stream>>>(bsum, boff, nbN);
  k_scan3<<<nbN, 256, 0, stream>>>(rowptr, boff, cursor, N, E);
  k_scatter<<<nbE, 256, 0, stream>>>(src, dst, dinv, cursor, esrc, eww, E);
  k_T<<<1, 256, 0, stream>>>(embed, Ws, T);
  k_prepW<<<3, 256, 0, stream>>>(Ws, wphi, wplo);
  k_bounds<<<nbN, 256, 0, stream>>>(batch, gstart, gend, N);

  // layer0 (rank-2) + gemm1 -> t_a
  k_l1_gemm<<<ntile, 512, 0, stream>>>(x, rowptr, esrc, eww, dinv, T, bs,
                                       wphi, wplo, t_a, N);
  // agg(b1)+gemm(W2) -> t_b ; agg(b2)+gemm(W3) -> t_a
  k_agg_gemm<<<ntile, 512, 0, stream>>>(t_a, rowptr, esrc, eww, dinv, bs + 128,
                                        wphi + 16384, wplo + 16384, t_b, N);
  k_agg_gemm<<<ntile, 512, 0, stream>>>(t_b, rowptr, esrc, eww, dinv, bs + 256,
                                        wphi + 32768, wplo + 32768, t_a, N);
  // final agg(b3) + mean-pool
  k_agg_pool<<<ntile, 512, 0, stream>>>(t_a, rowptr, esrc, eww, dinv, bs + 384,
                                        batch, pooled, N);
  k_out<<<G, 128, 0, stream>>>(pooled, gstart, gend, W_out, b_out, out, G);
}

// Round 9
// 350.473 us; speedup vs baseline: 1.3024x; 1.0571x over previous
//
#include <hip/hip_runtime.h>

typedef __attribute__((ext_vector_type(8))) short bf16x8;
typedef __attribute__((ext_vector_type(4))) float f32x4;
typedef __attribute__((ext_vector_type(2))) float f32x2;

// bf16 round-to-nearest-even
__device__ inline unsigned short bf16_rtn(float f) {
  unsigned u = __float_as_uint(f);
  unsigned r = u + 0x7fffu + ((u >> 16) & 1u);
  return (unsigned short)(r >> 16);
}

// split fp32 into hi/lo bf16 (for W only)
__device__ inline void split_bf16(float f, unsigned short& hi, unsigned short& lo) {
  hi = bf16_rtn(f);
  float fh = __uint_as_float((unsigned)hi << 16);
  lo = bf16_rtn(f - fh);
}

// fp8 e4m3 (OCP) pack/unpack via HW converters
__device__ inline unsigned char f_to_fp8(float f) {
  int r = __builtin_amdgcn_cvt_pk_fp8_f32(f, f, 0, false);
  return (unsigned char)(r & 0xff);
}
__device__ inline f32x2 fp8x2_to_f(unsigned short v) {
  return __builtin_amdgcn_cvt_pk_f32_fp8((int)v, false);
}

// ---------------- CSR construction ----------------

__global__ void k_hist(const int* __restrict__ dst, int* __restrict__ deg, int E) {
  int e = blockIdx.x * 256 + threadIdx.x;
  if (e < E) atomicAdd(&deg[dst[e]], 1);
}

__global__ void k_scan1(const int* __restrict__ deg, int* __restrict__ rowptr,
                        int* __restrict__ bsum, float* __restrict__ dinv, int N) {
  __shared__ int s[256];
  int t = threadIdx.x;
  int i = blockIdx.x * 256 + t;
  int v = (i < N) ? deg[i] : 0;
  if (i < N) dinv[i] = rsqrtf((float)v + 1.0f);
  s[t] = v;
  __syncthreads();
  for (int off = 1; off < 256; off <<= 1) {
    int u = (t >= off) ? s[t - off] : 0;
    __syncthreads();
    s[t] += u;
    __syncthreads();
  }
  if (i < N) rowptr[i] = s[t] - v;
  if (t == 255) bsum[blockIdx.x] = s[255];
}

__global__ void k_scan2(const int* __restrict__ bsum, int* __restrict__ boff, int nb) {
  __shared__ int s[512];
  int t = threadIdx.x;
  int v = (t < nb) ? bsum[t] : 0;
  s[t] = v;
  __syncthreads();
  for (int off = 1; off < 512; off <<= 1) {
    int u = (t >= off) ? s[t - off] : 0;
    __syncthreads();
    s[t] += u;
    __syncthreads();
  }
  boff[t] = s[t] - v;
}

__global__ void k_scan3(int* __restrict__ rowptr, const int* __restrict__ boff,
                        int* __restrict__ cursor, int N, int E) {
  int i = blockIdx.x * 256 + threadIdx.x;
  if (i < N) {
    int r = rowptr[i] + boff[i >> 8];
    rowptr[i] = r;
    cursor[i] = r;
  }
  if (i == 0) rowptr[N] = E;
}

__global__ void k_scatter(const int* __restrict__ src, const int* __restrict__ dst,
                          const float* __restrict__ dinv, int* __restrict__ cursor,
                          int* __restrict__ esrc, float* __restrict__ ew, int E) {
  int e = blockIdx.x * 256 + threadIdx.x;
  if (e >= E) return;
  int s = src[e], d = dst[e];
  float w = dinv[s] * dinv[d];
  int pos = atomicAdd(&cursor[d], 1);
  esrc[pos] = s;
  ew[pos] = w;
}

// ---------------- W swizzle + T precompute (fused) ----------------
// blocks 0..2: swizzle W layer l+1 into MFMA B-frag order (hi/lo bf16).
// block 3: T[r][c] = embed[r] @ W0.
__global__ void k_prepWT(const float* __restrict__ Ws, const float* __restrict__ embed,
                         unsigned short* __restrict__ wphi,
                         unsigned short* __restrict__ wplo,
                         float* __restrict__ T) {
  int l = blockIdx.x;
  if (l == 3) {
    int t = threadIdx.x;
    int r = t >> 7, c = t & 127;
    float acc = 0.f;
    for (int k = 0; k < 128; ++k)
      acc += embed[r * 128 + k] * Ws[k * 128 + c];
    T[r * 128 + c] = acc;
    return;
  }
  const float* W = Ws + (size_t)(l + 1) * 128 * 128;
  unsigned short* dh = wphi + (size_t)l * 16384;
  unsigned short* dl = wplo + (size_t)l * 16384;
  for (int idx = threadIdx.x; idx < 16384; idx += 256) {
    int j = idx & 7;
    int lane = (idx >> 3) & 63;
    int c = (idx >> 9) & 3;
    int ct = idx >> 11;
    int k = c * 32 + ((lane >> 4) * 8) + j;
    int n = ct * 16 + (lane & 15);
    unsigned short hi, lo;
    split_bf16(W[k * 128 + n], hi, lo);
    dh[idx] = hi;
    dl[idx] = lo;
  }
}

__global__ void k_bounds(const int* __restrict__ batch, int* __restrict__ gstart,
                         int* __restrict__ gend, int N) {
  int i = blockIdx.x * 256 + threadIdx.x;
  if (i >= N) return;
  int g = batch[i];
  if (i == 0 || batch[i - 1] != g) gstart[g] = i;
  if (i == N - 1 || batch[i + 1] != g) gend[g] = i + 1;
}

// ---------------- per-node gather (fp8 rows), unroll-4 batched loads ----------------
__device__ inline void gather_node(const unsigned char* __restrict__ tin,
                                   const int* __restrict__ esrc,
                                   const float* __restrict__ ew,
                                   int r0, int deg, int lane,
                                   float& a0, float& a1) {
  int dcap = deg < 64 ? deg : 64;
  int sl = 0; float wl = 0.f;
  if (lane < dcap) { sl = esrc[r0 + lane]; wl = ew[r0 + lane]; }
  a0 = 0.f; a1 = 0.f;
  int e = 0;
  for (; e + 4 <= dcap; e += 4) {
    int s0 = __shfl(sl, e, 64),     s1 = __shfl(sl, e + 1, 64);
    int s2 = __shfl(sl, e + 2, 64), s3 = __shfl(sl, e + 3, 64);
    float w0 = __shfl(wl, e, 64),     w1 = __shfl(wl, e + 1, 64);
    float w2 = __shfl(wl, e + 2, 64), w3 = __shfl(wl, e + 3, 64);
    unsigned short p0 = *(const unsigned short*)(tin + (size_t)s0 * 128 + 2 * lane);
    unsigned short p1 = *(const unsigned short*)(tin + (size_t)s1 * 128 + 2 * lane);
    unsigned short p2 = *(const unsigned short*)(tin + (size_t)s2 * 128 + 2 * lane);
    unsigned short p3 = *(const unsigned short*)(tin + (size_t)s3 * 128 + 2 * lane);
    f32x2 v0 = fp8x2_to_f(p0), v1 = fp8x2_to_f(p1);
    f32x2 v2 = fp8x2_to_f(p2), v3 = fp8x2_to_f(p3);
    a0 += w0 * v0.x + w1 * v1.x + w2 * v2.x + w3 * v3.x;
    a1 += w0 * v0.y + w1 * v1.y + w2 * v2.y + w3 * v3.y;
  }
  for (; e < dcap; ++e) {
    int s = __shfl(sl, e, 64);
    float w = __shfl(wl, e, 64);
    unsigned short p = *(const unsigned short*)(tin + (size_t)s * 128 + 2 * lane);
    f32x2 v = fp8x2_to_f(p);
    a0 += w * v.x;
    a1 += w * v.y;
  }
  for (int ee = r0 + 64; ee < r0 + deg; ++ee) {   // rare: deg > 64
    int s = esrc[ee];
    float w = ew[ee];
    unsigned short p = *(const unsigned short*)(tin + (size_t)s * 128 + 2 * lane);
    f32x2 v = fp8x2_to_f(p);
    a0 += w * v.x;
    a1 += w * v.y;
  }
}

// ---------------- shared MFMA phase (8 waves, ct = wave): tile = hT @ W' ----------------
__device__ inline void gemm_tile8(const unsigned short* hT,
                                  const unsigned short* __restrict__ wphi,
                                  const unsigned short* __restrict__ wplo,
                                  unsigned char* __restrict__ tout, int i0, int N) {
  int ct = threadIdx.x >> 6;     // wave 0..7 -> 16-col stripe
  int lane = threadIdx.x & 63;
  int q = lane >> 4;
  int m = lane & 15;
  const bf16x8* bh_base = (const bf16x8*)wphi;
  const bf16x8* bl_base = (const bf16x8*)wplo;

  f32x4 acc0 = (f32x4){0.f, 0.f, 0.f, 0.f};
  f32x4 acc1 = (f32x4){0.f, 0.f, 0.f, 0.f};

  #pragma unroll
  for (int c = 0; c < 4; ++c) {
    bf16x8 a0 = *(const bf16x8*)(hT + (m) * 136 + c * 32 + q * 8);
    bf16x8 a1 = *(const bf16x8*)(hT + (16 + m) * 136 + c * 32 + q * 8);
    bf16x8 bh = bh_base[(ct * 4 + c) * 64 + lane];
    bf16x8 bl = bl_base[(ct * 4 + c) * 64 + lane];
    acc0 = __builtin_amdgcn_mfma_f32_16x16x32_bf16(a0, bh, acc0, 0, 0, 0);
    acc0 = __builtin_amdgcn_mfma_f32_16x16x32_bf16(a0, bl, acc0, 0, 0, 0);
    acc1 = __builtin_amdgcn_mfma_f32_16x16x32_bf16(a1, bh, acc1, 0, 0, 0);
    acc1 = __builtin_amdgcn_mfma_f32_16x16x32_bf16(a1, bl, acc1, 0, 0, 0);
  }

  #pragma unroll
  for (int r = 0; r < 4; ++r) {
    int row0 = i0 + q * 4 + r;
    int row1 = row0 + 16;
    if (row0 < N) tout[(size_t)row0 * 128 + ct * 16 + m] = f_to_fp8(acc0[r]);
    if (row1 < N) tout[(size_t)row1 * 128 + ct * 16 + m] = f_to_fp8(acc1[r]);
  }
}

// ---------------- fused layer0 (rank-2) + gemm1: t1 = h1 @ W1 ----------------
__global__ __launch_bounds__(512)
void k_l1_gemm(const int* __restrict__ x, const int* __restrict__ rowptr,
               const int* __restrict__ esrc, const float* __restrict__ ew,
               const float* __restrict__ dinv, const float* __restrict__ T,
               const float* __restrict__ b0,
               const unsigned short* __restrict__ wphi,
               const unsigned short* __restrict__ wplo,
               unsigned char* __restrict__ tout, int N) {
  __shared__ unsigned short hT[32 * 136];
  int wave = threadIdx.x >> 6;
  int lane = threadIdx.x & 63;
  int i0 = blockIdx.x * 32;

  for (int j = wave * 4; j < wave * 4 + 4; ++j) {
    int i = i0 + j;
    if (i >= N) break;
    int r0 = rowptr[i], r1 = rowptr[i + 1];
    float c0 = 0.f, c1 = 0.f;
    for (int e = r0 + lane; e < r1; e += 64) {
      float w = ew[e];
      int s = esrc[e];
      if (x[s]) c1 += w; else c0 += w;
    }
    for (int mm = 32; mm >= 1; mm >>= 1) {
      c0 += __shfl_xor(c0, mm, 64);
      c1 += __shfl_xor(c1, mm, 64);
    }
    float di = dinv[i];
    float sn = di * di;
    if (x[i]) c1 += sn; else c0 += sn;
    float v0 = fmaxf(c0 * T[2 * lane]     + c1 * T[128 + 2 * lane]     + b0[2 * lane],     0.f);
    float v1 = fmaxf(c0 * T[2 * lane + 1] + c1 * T[128 + 2 * lane + 1] + b0[2 * lane + 1], 0.f);
    *(unsigned*)&hT[j * 136 + 2 * lane] = (unsigned)bf16_rtn(v0) | ((unsigned)bf16_rtn(v1) << 16);
  }
  __syncthreads();
  gemm_tile8(hT, wphi, wplo, tout, i0, N);
}

// ---------------- fused aggregate + gemm: t_next = relu(A t_in + b) @ W' ----------------
__global__ __launch_bounds__(512)
void k_agg_gemm(const unsigned char* __restrict__ tin,
                const int* __restrict__ rowptr,
                const int* __restrict__ esrc, const float* __restrict__ ew,
                const float* __restrict__ dinv, const float* __restrict__ bvec,
                const unsigned short* __restrict__ wphi,
                const unsigned short* __restrict__ wplo,
                unsigned char* __restrict__ tout, int N) {
  __shared__ unsigned short hT[32 * 136];
  int wave = threadIdx.x >> 6;
  int lane = threadIdx.x & 63;
  int i0 = blockIdx.x * 32;
  float2 bv = *(const float2*)(bvec + 2 * lane);

  for (int j = wave * 4; j < wave * 4 + 4; ++j) {
    int i = i0 + j;
    if (i >= N) break;
    int r0 = rowptr[i], r1 = rowptr[i + 1];
    float a0, a1;
    gather_node(tin, esrc, ew, r0, r1 - r0, lane, a0, a1);
    float di = dinv[i];
    float sn = di * di;
    unsigned short ps = *(const unsigned short*)(tin + (size_t)i * 128 + 2 * lane);
    f32x2 sv = fp8x2_to_f(ps);
    a0 += sn * sv.x;
    a1 += sn * sv.y;
    float v0 = fmaxf(a0 + bv.x, 0.f);
    float v1 = fmaxf(a1 + bv.y, 0.f);
    *(unsigned*)&hT[j * 136 + 2 * lane] = (unsigned)bf16_rtn(v0) | ((unsigned)bf16_rtn(v1) << 16);
  }
  __syncthreads();
  gemm_tile8(hT, wphi, wplo, tout, i0, N);
}

// ---------------- fused final aggregate + segment mean-pool ----------------
__global__ __launch_bounds__(512)
void k_agg_pool(const unsigned char* __restrict__ tin,
                const int* __restrict__ rowptr,
                const int* __restrict__ esrc, const float* __restrict__ ew,
                const float* __restrict__ dinv, const float* __restrict__ bvec,
                const int* __restrict__ batch,
                float* __restrict__ pooled, int N) {
  int wave = threadIdx.x >> 6;
  int lane = threadIdx.x & 63;
  int i0w = blockIdx.x * 32 + wave * 4;
  if (i0w >= N) return;
  float2 bv = *(const float2*)(bvec + 2 * lane);

  float acc0 = 0.f, acc1 = 0.f;
  int curg = batch[i0w];
  for (int n = 0; n < 4; ++n) {
    int i = i0w + n;
    if (i >= N) break;
    int r0 = rowptr[i], r1 = rowptr[i + 1];
    float a0, a1;
    gather_node(tin, esrc, ew, r0, r1 - r0, lane, a0, a1);
    float di = dinv[i];
    float sn = di * di;
    unsigned short ps = *(const unsigned short*)(tin + (size_t)i * 128 + 2 * lane);
    f32x2 sv = fp8x2_to_f(ps);
    a0 += sn * sv.x + bv.x;
    a1 += sn * sv.y + bv.y;
    int g = batch[i];
    if (g != curg) {
      atomicAdd(&pooled[curg * 128 + 2 * lane], acc0);
      atomicAdd(&pooled[curg * 128 + 2 * lane + 1], acc1);
      acc0 = 0.f; acc1 = 0.f;
      curg = g;
    }
    acc0 += a0;
    acc1 += a1;
  }
  atomicAdd(&pooled[curg * 128 + 2 * lane], acc0);
  atomicAdd(&pooled[curg * 128 + 2 * lane + 1], acc1);
}

// ---------------- output head ----------------
__global__ void k_out(const float* __restrict__ pooled, const int* __restrict__ gstart,
                      const int* __restrict__ gend, const float* __restrict__ W_out,
                      const float* __restrict__ b_out, float* __restrict__ out, int G) {
  __shared__ float sp[128];
  int g = blockIdx.x;
  int j = threadIdx.x;
  float cnt = (float)(gend[g] - gstart[g]);
  sp[j] = pooled[g * 128 + j] / fmaxf(cnt, 1.f);
  __syncthreads();
  if (j < 2) {
    float o = b_out[j];
    for (int k = 0; k < 128; ++k)
      o += sp[k] * W_out[k * 2 + j];
    out[g * 2 + j] = o;
  }
}

extern "C" void kernel_launch(void* const* d_in, const int* in_sizes, int n_in,
                              void* d_out, int out_size, void* d_ws, size_t ws_size,
                              hipStream_t stream) {
  const int*   x     = (const int*)d_in[0];
  const int*   ei    = (const int*)d_in[1];
  const int*   batch = (const int*)d_in[2];
  const float* embed = (const float*)d_in[3];
  const float* Ws    = (const float*)d_in[4];
  const float* bs    = (const float*)d_in[5];
  const float* W_out = (const float*)d_in[6];
  const float* b_out = (const float*)d_in[7];
  float* out = (float*)d_out;

  int N = in_sizes[2];
  int E = in_sizes[1] / 2;
  int G = out_size / 2;

  const int* src = ei;
  const int* dst = ei + E;

  char* w = (char*)d_ws;
  auto alloc = [&](size_t bytes) {
    char* p = w;
    w += (bytes + 255) & ~(size_t)255;
    return p;
  };
  int*   deg    = (int*)  alloc((size_t)N * 4);
  float* dinv   = (float*)alloc((size_t)N * 4);
  int*   rowptr = (int*)  alloc((size_t)(N + 1) * 4);
  int*   cursor = (int*)  alloc((size_t)N * 4);
  int*   bsum   = (int*)  alloc(512 * 4);
  int*   boff   = (int*)  alloc(512 * 4);
  // gstart/gend/pooled contiguous -> single memset
  int*   gstart = (int*)  alloc((size_t)G * 4);
  int*   gend   = (int*)  alloc((size_t)G * 4);
  float* pooled = (float*)alloc((size_t)G * 128 * 4);
  float* T      = (float*)alloc(256 * 4);
  unsigned short* wphi = (unsigned short*)alloc((size_t)3 * 16384 * 2);
  unsigned short* wplo = (unsigned short*)alloc((size_t)3 * 16384 * 2);
  int*   esrc   = (int*)  alloc((size_t)E * 4);
  float* eww    = (float*)alloc((size_t)E * 4);
  unsigned char* t_a = (unsigned char*)alloc((size_t)N * 128);
  unsigned char* t_b = (unsigned char*)alloc((size_t)N * 128);

  int nbN = (N + 255) / 256;
  int nbE = (E + 255) / 256;
  int ntile = (N + 31) / 32;

  size_t gzero = (size_t)((char*)pooled - (char*)gstart) + (size_t)G * 128 * 4;
  hipMemsetAsync(deg, 0, (size_t)N * 4, stream);
  hipMemsetAsync(gstart, 0, gzero, stream);

  k_hist<<<nbE, 256, 0, stream>>>(dst, deg, E);
  k_scan1<<<nbN, 256, 0, stream>>>(deg, rowptr, bsum, dinv, N);
  k_scan2<<<1, 512, 0, stream>>>(bsum, boff, nbN);
  k_scan3<<<nbN, 256, 0, stream>>>(rowptr, boff, cursor, N, E);
  k_scatter<<<nbE, 256, 0, stream>>>(src, dst, dinv, cursor, esrc, eww, E);
  k_prepWT<<<4, 256, 0, stream>>>(Ws, embed, wphi, wplo, T);
  k_bounds<<<nbN, 256, 0, stream>>>(batch, gstart, gend, N);

  // layer0 (rank-2) + gemm1 -> t_a
  k_l1_gemm<<<ntile, 512, 0, stream>>>(x, rowptr, esrc, eww, dinv, T, bs,
                                       wphi, wplo, t_a, N);
  // agg(b1)+gemm(W2) -> t_b ; agg(b2)+gemm(W3) -> t_a
  k_agg_gemm<<<ntile, 512, 0, stream>>>(t_a, rowptr, esrc, eww, dinv, bs + 128,
                                        wphi + 16384, wplo + 16384, t_b, N);
  k_agg_gemm<<<ntile, 512, 0, stream>>>(t_b, rowptr, esrc, eww, dinv, bs + 256,
                                        wphi + 32768, wplo + 32768, t_a, N);
  // final agg(b3) + mean-pool
  k_agg_pool<<<ntile, 512, 0, stream>>>(t_a, rowptr, esrc, eww, dinv, bs + 384,
                                        batch, pooled, N);
  k_out<<<G, 128, 0, stream>>>(pooled, gstart, gend, W_out, b_out, out, G);
}